// Round 8
// baseline (208.225 us; speedup 1.0000x reference)
//
#include <hip/hip_runtime.h>
#include <hip/hip_cooperative_groups.h>

namespace cg = cooperative_groups;

// Signature-kernel MMD, fused. R20 = R19 (68.14us verified) + ONE delta:
// cooperative single-kernel launch. The separate reduce_kernel dispatch is
// replaced by grid.sync() + block-0 inline reduction (same loads, same
// order -> bit-identical). Geometry is exactly co-resident: 768 blocks =
// 3/CU x 256 CU (LDS 43.5KB <= 53.3, VGPR capped by launch_bounds(256,3)).
// R19 lesson kept: v_pk_* f32 are HALF-RATE on CDNA4 (157.3TF spec has no
// pk doubling) - pk body retained (neutral, verified).

constexpr int PAD2 = 128;   // front pad bytes
constexpr int BNA  = 4800;  // per-pair buffer in fp16 elems (9600 B, 16B-mult)

// write byte offset of (row r, col c=lane): 128 + 146r + A(r) + 2c
#define WOFF(r) (PAD2 + 146 * (r) + ((((r) >> 3) & 7) << 4))

typedef float f32x2 __attribute__((ext_vector_type(2)));

__device__ __forceinline__ float dpp_shr1(float v) {
    // result[l] = src[l-1], result[0] = 0   (wave_shr:1)
    return __builtin_bit_cast(float,
        __builtin_amdgcn_update_dpp(0, __builtin_bit_cast(int, v), 0x138, 0xF, 0xF, true));
}
__device__ __forceinline__ float dpp_shl1(float v) {
    // result[l] = src[l+1], result[63] = 0  (wave_shl:1)
    return __builtin_bit_cast(float,
        __builtin_amdgcn_update_dpp(0, __builtin_bit_cast(int, v), 0x130, 0xF, 0xF, true));
}
__device__ __forceinline__ float dot4(float4 a, float4 b) {
    return a.x * b.x + a.y * b.y + a.z * b.z + a.w * b.w;
}
// Convert-and-fold from packed u32: (float)f16 * 0.25 - 1.0. Exact.
__device__ __forceinline__ float cvtLO(unsigned u, float q25) {
    float r;
    asm("v_fma_mix_f32 %0, %1, %2, -1.0 op_sel_hi:[1,0,0]"
        : "=v"(r) : "v"(u), "s"(q25));
    return r;
}
__device__ __forceinline__ float cvtHI(unsigned u, float q25) {
    float r;
    asm("v_fma_mix_f32 %0, %1, %2, -1.0 op_sel:[1,0,0] op_sel_hi:[1,0,0]"
        : "=v"(r) : "v"(u), "s"(q25));
    return r;
}
// Packed FP32 (CDNA4: half-rate, neutral vs scalar - kept for code size).
__device__ __forceinline__ f32x2 pk_add(f32x2 a, f32x2 b) {
    f32x2 r;
    asm("v_pk_add_f32 %0, %1, %2" : "=v"(r) : "v"(a), "v"(b));
    return r;
}
__device__ __forceinline__ f32x2 pk_fma(f32x2 a, f32x2 b, f32x2 c) {
    f32x2 r;
    asm("v_pk_fma_f32 %0, %1, %2, %3" : "=v"(r) : "v"(a), "v"(b), "v"(c));
    return r;
}

// One PDE substep (one antidiagonal), packed. Scalar-equivalent (verified
// R3/R6 structure): cE = up1 + p1E + up2*eF; cO = p1E + p1O + p2E*oF.
#define PSUB {                                  \
    f32x2 W;                                    \
    W.x = dpp_shr1(P.y);                        \
    W.y = P.x;                                  \
    P = pk_fma(U, F, pk_add(W, P));             \
    U = W; }

// One body = diagonals 2k-1, 2k. cvtexpr supplies of(k) = 0.25*binc - 1.
#define PBODYv(cvtexpr) {                       \
    F.x = dpp_shr1(F.y);                        \
    PSUB                                        \
    F.y = (cvtexpr);                            \
    PSUB }

// 8 bodies off one uint4 chunk (slots x.lo, x.hi, y.lo, y.hi, z.lo, ...).
#define PBODY8(ch) {                                     \
    PBODYv(cvtLO(ch.x, q25)) PBODYv(cvtHI(ch.x, q25))    \
    PBODYv(cvtLO(ch.y, q25)) PBODYv(cvtHI(ch.y, q25))    \
    PBODYv(cvtLO(ch.z, q25)) PBODYv(cvtHI(ch.z, q25))    \
    PBODYv(cvtLO(ch.w, q25)) PBODYv(cvtHI(ch.w, q25)) }

__global__ __launch_bounds__(256, 3) void sigpde_kernel(const float* __restrict__ x,
                                                        const float* __restrict__ y,
                                                        float* __restrict__ pws,
                                                        float* __restrict__ out) {
    __shared__ __align__(16) _Float16 binc[4][BNA];   // 38400 B
    __shared__ float4 xs[4][64];                      //  4096 B
    __shared__ float  xxs[4][64];                     //  1024 B
    __shared__ float  ws[4];                          //    16 B

    const int lane = threadIdx.x & 63;
    const int wid  = threadIdx.x >> 6;
    const int p = blockIdx.x * 4 + wid;     // 0..3071
    const int g = p >> 10;                  // 0: xx, 1: xy, 2: yy
    const int q = p & 1023;
    const int a = q >> 5, b = q & 31;
    const float* Ab = (g == 2) ? y : x;
    const float* Bb = (g == 0) ? x : y;

    _Float16* bw = &binc[wid][0];

    const float C   = -0.72134752044448170f;  // -0.5*log2(e)
    const float L2E =  1.44269504088896340f;  // log2(e) = -2*C

    float4 xa = ((const float4*)(Ab + a * 256))[lane];
    float4 yv = ((const float4*)(Bb + b * 256))[lane];
    xs[wid][lane]  = xa;
    xxs[wid][lane] = C * dot4(xa, xa);        // pre-scaled by C
    const float cyy = C * dot4(yv, yv);       // lane-constant, pre-scaled

    {   // zero this wave's buffer (pads/gaps/overreads must be finite)
        uint4* z = (uint4*)bw;
        const uint4 zz = {0u, 0u, 0u, 0u};
        #pragma unroll
        for (int j = 0; j < 9; ++j) z[lane + 64 * j] = zz;  // 576 of 600
        if (lane < 24) z[576 + lane] = zz;                   // tail
    }
    // No barrier anywhere: all LDS is wave-private; same-wave ds ordering
    // is guaranteed via lgkmcnt.

    // De-phase the 3 co-resident blocks per CU (one-time, <=1280 cyc).
    {
        const int ph = blockIdx.x % 3;
        if (ph == 1)      __builtin_amdgcn_s_sleep(10);  // ~640 cyc
        else if (ph == 2) __builtin_amdgcn_s_sleep(20);  // ~1280 cyc
    }

    // Gram + double increments (column = lane), verified R6/R16:
    // gv = exp2(fma(xy, log2e, cxx+cyy)); store RAW (d - dp) fp16 at the
    // skewed row offset WOFF(u-1) + 2*lane (compile-time per u).
    char* bwh = (char*)bw + 2 * lane;
    float dp;
    {   // peeled u = 0
        float4 x0 = xs[wid][0];
        float g0 = __builtin_amdgcn_exp2f(
            __builtin_fmaf(dot4(x0, yv), L2E, xxs[wid][0] + cyy));
        dp = dpp_shl1(g0) - g0;
    }
    #pragma unroll
    for (int u = 1; u < 64; ++u) {
        float4 xu = xs[wid][u];            // broadcast read
        float gv = __builtin_amdgcn_exp2f(
            __builtin_fmaf(dot4(xu, yv), L2E, xxs[wid][u] + cyy));
        float d = dpp_shl1(gv) - gv;
        *(_Float16*)(bwh + WOFF(u - 1)) = (_Float16)(d - dp);
        dp = d;
    }

    // Goursat PDE: lane owns rows iE=2l, iO=2l+1; body k = diags 2k-1,2k.
    // Lane l's factor stream = row l of binc, read as b128 chunks of 8 fp16
    // at base 128 + 144*lane + A(lane) (16B-aligned, bank-skewed).
    const char* oaB = (const char*)bw + (PAD2 + 144 * lane + (((lane >> 3) & 7) << 4));
    const float q25 = 0.25f;                // SGPR for v_fma_mix

    f32x2 P = { (lane == 0) ? 1.0f : 0.0f, 0.0f };  // (p1E, p1O); K[0,0]=1
    f32x2 U = { 0.0f, 0.0f };                        // (up2, p2E)
    f32x2 F = { -1.0f, -1.0f };                      // F.y = oF(0) = -1

    // 3 chunks in flight (load-to-use distance = 2 full chunk-iterations).
    uint4 cA = *(const uint4*)(oaB +  0);
    uint4 cB = *(const uint4*)(oaB + 16);
    uint4 cC = *(const uint4*)(oaB + 32);

    #pragma unroll
    for (int c = 0; c < 15; ++c) {
        // consume chunk c: bodies 8c+1 .. 8c+8
        PBODY8(cA)
        // rotate + prefetch chunk c+3 (chunks 0..15 cover oA[0..127])
        cA = cB; cB = cC;
        if (c <= 12) cC = *(const uint4*)(oaB + 16 * (c + 3));
    }
    // tail: bodies 121..126 from chunk 15 (slots x.lo .. z.hi)
    PBODYv(cvtLO(cA.x, q25)) PBODYv(cvtHI(cA.x, q25))
    PBODYv(cvtLO(cA.y, q25)) PBODYv(cvtHI(cA.y, q25))
    PBODYv(cvtLO(cA.z, q25)) PBODYv(cvtHI(cA.z, q25))

    // K[126,126] = lane 63's E slot after diagonal 252. Plain store.
    if (lane == 63) {
        float w = (g == 1) ? (-2.0f / 1024.0f) : (1.0f / 1024.0f);
        pws[p] = w * P.x;
    }

    // Fused reduction: grid-wide sync, then block 0 sums the 3072 weighted
    // partials (768 float4 loads, identical order to the old reduce_kernel).
    __threadfence();
    cg::this_grid().sync();
    if (blockIdx.x == 0) {
        float s = 0.0f;
        const float4* v = (const float4*)pws;
        for (int i = threadIdx.x; i < 768; i += 256) {
            float4 t = v[i];
            s += (t.x + t.y) + (t.z + t.w);
        }
        for (int off = 32; off > 0; off >>= 1) s += __shfl_down(s, off);
        if (lane == 0) ws[wid] = s;
        __syncthreads();
        if (threadIdx.x == 0) out[0] = (ws[0] + ws[1]) + (ws[2] + ws[3]);
    }
}

extern "C" void kernel_launch(void* const* d_in, const int* in_sizes, int n_in,
                              void* d_out, int out_size, void* d_ws, size_t ws_size,
                              hipStream_t stream) {
    const float* x = (const float*)d_in[0];
    const float* y = (const float*)d_in[1];
    float* out = (float*)d_out;
    float* pws = (float*)d_ws;    // 3072 floats = 12 KB << ws_size
    (void)in_sizes; (void)n_in; (void)out_size; (void)ws_size;

    void* args[] = { (void*)&x, (void*)&y, (void*)&pws, (void*)&out };
    hipLaunchCooperativeKernel((const void*)sigpde_kernel,
                               dim3(768), dim3(256), args, 0u, stream);
}

// Round 9
// 109.450 us; speedup vs baseline: 1.9025x; 1.9025x over previous
//
#include <hip/hip_runtime.h>

// Signature-kernel MMD, fused. R21 = R19 (68.14us verified; R20's
// hipLaunchCooperativeKernel REVERTED - the coop launch/grid-sync path cost
// +140us at 6.5% VALUBusy) + ONE delta: last-block reduction. A static
// __device__ ticket counts finished blocks; the 768th block reduces the
// 3072 partials inline (identical load order -> bit-identical) and resets
// the ticket for the next bench iteration. Removes the reduce dispatch;
// 767 blocks exit early (no grid-wide spin).
// R20 counter notes: SQ_LDS_BANK_CONFLICT=3072x128 = 8cyc x 16 b128 reads
// = intrinsic wave64 ds_read_b128 serialization (~0.6us total, not fixable);
// VGPR=68, 3 blocks/CU as designed.

constexpr int PAD2 = 128;   // front pad bytes
constexpr int BNA  = 4800;  // per-pair buffer in fp16 elems (9600 B, 16B-mult)

// write byte offset of (row r, col c=lane): 128 + 146r + A(r) + 2c
#define WOFF(r) (PAD2 + 146 * (r) + ((((r) >> 3) & 7) << 4))

typedef float f32x2 __attribute__((ext_vector_type(2)));

__device__ int g_ticket = 0;   // module-load init; self-reset each launch

__device__ __forceinline__ float dpp_shr1(float v) {
    // result[l] = src[l-1], result[0] = 0   (wave_shr:1)
    return __builtin_bit_cast(float,
        __builtin_amdgcn_update_dpp(0, __builtin_bit_cast(int, v), 0x138, 0xF, 0xF, true));
}
__device__ __forceinline__ float dpp_shl1(float v) {
    // result[l] = src[l+1], result[63] = 0  (wave_shl:1)
    return __builtin_bit_cast(float,
        __builtin_amdgcn_update_dpp(0, __builtin_bit_cast(int, v), 0x130, 0xF, 0xF, true));
}
__device__ __forceinline__ float dot4(float4 a, float4 b) {
    return a.x * b.x + a.y * b.y + a.z * b.z + a.w * b.w;
}
// Convert-and-fold from packed u32: (float)f16 * 0.25 - 1.0. Exact.
__device__ __forceinline__ float cvtLO(unsigned u, float q25) {
    float r;
    asm("v_fma_mix_f32 %0, %1, %2, -1.0 op_sel_hi:[1,0,0]"
        : "=v"(r) : "v"(u), "s"(q25));
    return r;
}
__device__ __forceinline__ float cvtHI(unsigned u, float q25) {
    float r;
    asm("v_fma_mix_f32 %0, %1, %2, -1.0 op_sel:[1,0,0] op_sel_hi:[1,0,0]"
        : "=v"(r) : "v"(u), "s"(q25));
    return r;
}
// Packed FP32 (CDNA4: half-rate, neutral vs scalar - verified R19).
__device__ __forceinline__ f32x2 pk_add(f32x2 a, f32x2 b) {
    f32x2 r;
    asm("v_pk_add_f32 %0, %1, %2" : "=v"(r) : "v"(a), "v"(b));
    return r;
}
__device__ __forceinline__ f32x2 pk_fma(f32x2 a, f32x2 b, f32x2 c) {
    f32x2 r;
    asm("v_pk_fma_f32 %0, %1, %2, %3" : "=v"(r) : "v"(a), "v"(b), "v"(c));
    return r;
}

// One PDE substep (one antidiagonal), packed. Scalar-equivalent (verified
// R3/R6 structure): cE = up1 + p1E + up2*eF; cO = p1E + p1O + p2E*oF.
#define PSUB {                                  \
    f32x2 W;                                    \
    W.x = dpp_shr1(P.y);                        \
    W.y = P.x;                                  \
    P = pk_fma(U, F, pk_add(W, P));             \
    U = W; }

// One body = diagonals 2k-1, 2k. cvtexpr supplies of(k) = 0.25*binc - 1.
#define PBODYv(cvtexpr) {                       \
    F.x = dpp_shr1(F.y);                        \
    PSUB                                        \
    F.y = (cvtexpr);                            \
    PSUB }

// 8 bodies off one uint4 chunk (slots x.lo, x.hi, y.lo, y.hi, z.lo, ...).
#define PBODY8(ch) {                                     \
    PBODYv(cvtLO(ch.x, q25)) PBODYv(cvtHI(ch.x, q25))    \
    PBODYv(cvtLO(ch.y, q25)) PBODYv(cvtHI(ch.y, q25))    \
    PBODYv(cvtLO(ch.z, q25)) PBODYv(cvtHI(ch.z, q25))    \
    PBODYv(cvtLO(ch.w, q25)) PBODYv(cvtHI(ch.w, q25)) }

__global__ __launch_bounds__(256, 3) void sigpde_kernel(const float* __restrict__ x,
                                                        const float* __restrict__ y,
                                                        float* __restrict__ pws,
                                                        float* __restrict__ out) {
    __shared__ __align__(16) _Float16 binc[4][BNA];   // 38400 B
    __shared__ float4 xs[4][64];                      //  4096 B
    __shared__ float  xxs[4][64];                     //  1024 B
    __shared__ float  ws[4];
    __shared__ int    isLast;

    const int lane = threadIdx.x & 63;
    const int wid  = threadIdx.x >> 6;
    const int p = blockIdx.x * 4 + wid;     // 0..3071
    const int g = p >> 10;                  // 0: xx, 1: xy, 2: yy
    const int q = p & 1023;
    const int a = q >> 5, b = q & 31;
    const float* Ab = (g == 2) ? y : x;
    const float* Bb = (g == 0) ? x : y;

    _Float16* bw = &binc[wid][0];

    const float C   = -0.72134752044448170f;  // -0.5*log2(e)
    const float L2E =  1.44269504088896340f;  // log2(e) = -2*C

    float4 xa = ((const float4*)(Ab + a * 256))[lane];
    float4 yv = ((const float4*)(Bb + b * 256))[lane];
    xs[wid][lane]  = xa;
    xxs[wid][lane] = C * dot4(xa, xa);        // pre-scaled by C
    const float cyy = C * dot4(yv, yv);       // lane-constant, pre-scaled

    {   // zero this wave's buffer (pads/gaps/overreads must be finite)
        uint4* z = (uint4*)bw;
        const uint4 zz = {0u, 0u, 0u, 0u};
        #pragma unroll
        for (int j = 0; j < 9; ++j) z[lane + 64 * j] = zz;  // 576 of 600
        if (lane < 24) z[576 + lane] = zz;                   // tail
    }
    // No barrier in the compute: all LDS is wave-private; same-wave ds
    // ordering is guaranteed via lgkmcnt.

    // De-phase the 3 co-resident blocks per CU (one-time, <=1280 cyc).
    {
        const int ph = blockIdx.x % 3;
        if (ph == 1)      __builtin_amdgcn_s_sleep(10);  // ~640 cyc
        else if (ph == 2) __builtin_amdgcn_s_sleep(20);  // ~1280 cyc
    }

    // Gram + double increments (column = lane), verified R6/R16:
    // gv = exp2(fma(xy, log2e, cxx+cyy)); store RAW (d - dp) fp16 at the
    // skewed row offset WOFF(u-1) + 2*lane (compile-time per u).
    char* bwh = (char*)bw + 2 * lane;
    float dp;
    {   // peeled u = 0
        float4 x0 = xs[wid][0];
        float g0 = __builtin_amdgcn_exp2f(
            __builtin_fmaf(dot4(x0, yv), L2E, xxs[wid][0] + cyy));
        dp = dpp_shl1(g0) - g0;
    }
    #pragma unroll
    for (int u = 1; u < 64; ++u) {
        float4 xu = xs[wid][u];            // broadcast read
        float gv = __builtin_amdgcn_exp2f(
            __builtin_fmaf(dot4(xu, yv), L2E, xxs[wid][u] + cyy));
        float d = dpp_shl1(gv) - gv;
        *(_Float16*)(bwh + WOFF(u - 1)) = (_Float16)(d - dp);
        dp = d;
    }

    // Goursat PDE: lane owns rows iE=2l, iO=2l+1; body k = diags 2k-1,2k.
    // Lane l's factor stream = row l of binc, read as b128 chunks of 8 fp16
    // at base 128 + 144*lane + A(lane) (16B-aligned, bank-skewed).
    const char* oaB = (const char*)bw + (PAD2 + 144 * lane + (((lane >> 3) & 7) << 4));
    const float q25 = 0.25f;                // SGPR for v_fma_mix

    f32x2 P = { (lane == 0) ? 1.0f : 0.0f, 0.0f };  // (p1E, p1O); K[0,0]=1
    f32x2 U = { 0.0f, 0.0f };                        // (up2, p2E)
    f32x2 F = { -1.0f, -1.0f };                      // F.y = oF(0) = -1

    // 3 chunks in flight (load-to-use distance = 2 full chunk-iterations).
    uint4 cA = *(const uint4*)(oaB +  0);
    uint4 cB = *(const uint4*)(oaB + 16);
    uint4 cC = *(const uint4*)(oaB + 32);

    #pragma unroll
    for (int c = 0; c < 15; ++c) {
        // consume chunk c: bodies 8c+1 .. 8c+8
        PBODY8(cA)
        // rotate + prefetch chunk c+3 (chunks 0..15 cover oA[0..127])
        cA = cB; cB = cC;
        if (c <= 12) cC = *(const uint4*)(oaB + 16 * (c + 3));
    }
    // tail: bodies 121..126 from chunk 15 (slots x.lo .. z.hi)
    PBODYv(cvtLO(cA.x, q25)) PBODYv(cvtHI(cA.x, q25))
    PBODYv(cvtLO(cA.y, q25)) PBODYv(cvtHI(cA.y, q25))
    PBODYv(cvtLO(cA.z, q25)) PBODYv(cvtHI(cA.z, q25))

    // K[126,126] = lane 63's E slot after diagonal 252. Store + release
    // fence so the partial is LLC-visible before this block's ticket bump.
    if (lane == 63) {
        float w = (g == 1) ? (-2.0f / 1024.0f) : (1.0f / 1024.0f);
        pws[p] = w * P.x;
        __threadfence();                    // agent-release (L2 writeback)
    }

    // Last-block reduction (replaces the reduce_kernel dispatch).
    __syncthreads();
    if (threadIdx.x == 0) isLast = (atomicAdd(&g_ticket, 1) == 767);
    __syncthreads();
    if (isLast) {
        __threadfence();                    // acquire (invalidate L1/L2)
        float s = 0.0f;
        const float4* v = (const float4*)pws;
        for (int i = threadIdx.x; i < 768; i += 256) {
            float4 t = v[i];
            s += (t.x + t.y) + (t.z + t.w);
        }
        for (int off = 32; off > 0; off >>= 1) s += __shfl_down(s, off);
        if (lane == 0) ws[wid] = s;
        __syncthreads();
        if (threadIdx.x == 0) {
            out[0] = (ws[0] + ws[1]) + (ws[2] + ws[3]);
            atomicExch(&g_ticket, 0);       // reset for next bench iteration
        }
    }
}

extern "C" void kernel_launch(void* const* d_in, const int* in_sizes, int n_in,
                              void* d_out, int out_size, void* d_ws, size_t ws_size,
                              hipStream_t stream) {
    const float* x = (const float*)d_in[0];
    const float* y = (const float*)d_in[1];
    float* out = (float*)d_out;
    float* pws = (float*)d_ws;    // 3072 floats = 12 KB << ws_size
    (void)in_sizes; (void)n_in; (void)out_size; (void)ws_size;

    hipLaunchKernelGGL(sigpde_kernel, dim3(768), dim3(256), 0, stream,
                       x, y, pws, out);
}

// Round 11
// 68.203 us; speedup vs baseline: 3.0530x; 1.6048x over previous
//
#include <hip/hip_runtime.h>

// Signature-kernel MMD, fused. R22 = pure REVERT to R19 (68.14us verified).
// R20 (hipLaunchCooperativeKernel fusion): +140us - runtime grid-sync spin,
//   VALUBusy 6.5%. REJECTED.
// R21 (ticket/last-block fusion): +41us - device-scope __threadfence() emits
//   L2 writeback/invalidate per block (x768) + single-address ticket atomic;
//   sigpde 59.5us at 15% VALUBusy (same ~9us absolute VALU as ever).
//   REJECTED. Lesson (measured twice): in-kernel cross-block sync on MI355X
//   costs >> a kernel launch; the two-dispatch structure is optimal.
// Steady-state model: 39.4us harness poison-fill (85% HBM, unremovable)
//   + ~23us sigpde (VALU-issue bound at DVFS-reduced clock)
//   + ~5us reduce+launch gaps. Only direct VALU-cycle removal pays
//   (R14/R16/R17/R18 = -6.3us); latency/structure changes are neutral or
//   negative (R15/R19-pk/R20/R21). PDE body is ~2 VALU/cell + 1 DPP/2cells,
//   near the serial-recurrence minimum. SQ_LDS_BANK_CONFLICT = 8cyc x 16
//   b128 reads = intrinsic wave64 serialization (~0.6us, not fixable).

constexpr int PAD2 = 128;   // front pad bytes
constexpr int BNA  = 4800;  // per-pair buffer in fp16 elems (9600 B, 16B-mult)

// write byte offset of (row r, col c=lane): 128 + 146r + A(r) + 2c
#define WOFF(r) (PAD2 + 146 * (r) + ((((r) >> 3) & 7) << 4))

typedef float f32x2 __attribute__((ext_vector_type(2)));

__device__ __forceinline__ float dpp_shr1(float v) {
    // result[l] = src[l-1], result[0] = 0   (wave_shr:1)
    return __builtin_bit_cast(float,
        __builtin_amdgcn_update_dpp(0, __builtin_bit_cast(int, v), 0x138, 0xF, 0xF, true));
}
__device__ __forceinline__ float dpp_shl1(float v) {
    // result[l] = src[l+1], result[63] = 0  (wave_shl:1)
    return __builtin_bit_cast(float,
        __builtin_amdgcn_update_dpp(0, __builtin_bit_cast(int, v), 0x130, 0xF, 0xF, true));
}
__device__ __forceinline__ float dot4(float4 a, float4 b) {
    return a.x * b.x + a.y * b.y + a.z * b.z + a.w * b.w;
}
// Convert-and-fold from packed u32: (float)f16 * 0.25 - 1.0. Exact.
__device__ __forceinline__ float cvtLO(unsigned u, float q25) {
    float r;
    asm("v_fma_mix_f32 %0, %1, %2, -1.0 op_sel_hi:[1,0,0]"
        : "=v"(r) : "v"(u), "s"(q25));
    return r;
}
__device__ __forceinline__ float cvtHI(unsigned u, float q25) {
    float r;
    asm("v_fma_mix_f32 %0, %1, %2, -1.0 op_sel:[1,0,0] op_sel_hi:[1,0,0]"
        : "=v"(r) : "v"(u), "s"(q25));
    return r;
}
// Packed FP32 (CDNA4: half-rate, neutral vs scalar - verified R19).
__device__ __forceinline__ f32x2 pk_add(f32x2 a, f32x2 b) {
    f32x2 r;
    asm("v_pk_add_f32 %0, %1, %2" : "=v"(r) : "v"(a), "v"(b));
    return r;
}
__device__ __forceinline__ f32x2 pk_fma(f32x2 a, f32x2 b, f32x2 c) {
    f32x2 r;
    asm("v_pk_fma_f32 %0, %1, %2, %3" : "=v"(r) : "v"(a), "v"(b), "v"(c));
    return r;
}

// One PDE substep (one antidiagonal), packed. Scalar-equivalent (verified
// R3/R6 structure): cE = up1 + p1E + up2*eF; cO = p1E + p1O + p2E*oF.
#define PSUB {                                  \
    f32x2 W;                                    \
    W.x = dpp_shr1(P.y);                        \
    W.y = P.x;                                  \
    P = pk_fma(U, F, pk_add(W, P));             \
    U = W; }

// One body = diagonals 2k-1, 2k. cvtexpr supplies of(k) = 0.25*binc - 1.
#define PBODYv(cvtexpr) {                       \
    F.x = dpp_shr1(F.y);                        \
    PSUB                                        \
    F.y = (cvtexpr);                            \
    PSUB }

// 8 bodies off one uint4 chunk (slots x.lo, x.hi, y.lo, y.hi, z.lo, ...).
#define PBODY8(ch) {                                     \
    PBODYv(cvtLO(ch.x, q25)) PBODYv(cvtHI(ch.x, q25))    \
    PBODYv(cvtLO(ch.y, q25)) PBODYv(cvtHI(ch.y, q25))    \
    PBODYv(cvtLO(ch.z, q25)) PBODYv(cvtHI(ch.z, q25))    \
    PBODYv(cvtLO(ch.w, q25)) PBODYv(cvtHI(ch.w, q25)) }

__global__ __launch_bounds__(256, 3) void sigpde_kernel(const float* __restrict__ x,
                                                        const float* __restrict__ y,
                                                        float* __restrict__ pws) {
    __shared__ __align__(16) _Float16 binc[4][BNA];   // 38400 B
    __shared__ float4 xs[4][64];                      //  4096 B
    __shared__ float  xxs[4][64];                     //  1024 B

    const int lane = threadIdx.x & 63;
    const int wid  = threadIdx.x >> 6;
    const int p = blockIdx.x * 4 + wid;     // 0..3071
    const int g = p >> 10;                  // 0: xx, 1: xy, 2: yy
    const int q = p & 1023;
    const int a = q >> 5, b = q & 31;
    const float* Ab = (g == 2) ? y : x;
    const float* Bb = (g == 0) ? x : y;

    _Float16* bw = &binc[wid][0];

    const float C   = -0.72134752044448170f;  // -0.5*log2(e)
    const float L2E =  1.44269504088896340f;  // log2(e) = -2*C

    float4 xa = ((const float4*)(Ab + a * 256))[lane];
    float4 yv = ((const float4*)(Bb + b * 256))[lane];
    xs[wid][lane]  = xa;
    xxs[wid][lane] = C * dot4(xa, xa);        // pre-scaled by C
    const float cyy = C * dot4(yv, yv);       // lane-constant, pre-scaled

    {   // zero this wave's buffer (pads/gaps/overreads must be finite)
        uint4* z = (uint4*)bw;
        const uint4 zz = {0u, 0u, 0u, 0u};
        #pragma unroll
        for (int j = 0; j < 9; ++j) z[lane + 64 * j] = zz;  // 576 of 600
        if (lane < 24) z[576 + lane] = zz;                   // tail
    }
    // No barrier anywhere: all LDS is wave-private; same-wave ds ordering
    // is guaranteed via lgkmcnt.

    // De-phase the 3 co-resident blocks per CU (one-time, <=1280 cyc).
    {
        const int ph = blockIdx.x % 3;
        if (ph == 1)      __builtin_amdgcn_s_sleep(10);  // ~640 cyc
        else if (ph == 2) __builtin_amdgcn_s_sleep(20);  // ~1280 cyc
    }

    // Gram + double increments (column = lane), verified R6/R16:
    // gv = exp2(fma(xy, log2e, cxx+cyy)); store RAW (d - dp) fp16 at the
    // skewed row offset WOFF(u-1) + 2*lane (compile-time per u).
    char* bwh = (char*)bw + 2 * lane;
    float dp;
    {   // peeled u = 0
        float4 x0 = xs[wid][0];
        float g0 = __builtin_amdgcn_exp2f(
            __builtin_fmaf(dot4(x0, yv), L2E, xxs[wid][0] + cyy));
        dp = dpp_shl1(g0) - g0;
    }
    #pragma unroll
    for (int u = 1; u < 64; ++u) {
        float4 xu = xs[wid][u];            // broadcast read
        float gv = __builtin_amdgcn_exp2f(
            __builtin_fmaf(dot4(xu, yv), L2E, xxs[wid][u] + cyy));
        float d = dpp_shl1(gv) - gv;
        *(_Float16*)(bwh + WOFF(u - 1)) = (_Float16)(d - dp);
        dp = d;
    }

    // Goursat PDE: lane owns rows iE=2l, iO=2l+1; body k = diags 2k-1,2k.
    // Lane l's factor stream = row l of binc, read as b128 chunks of 8 fp16
    // at base 128 + 144*lane + A(lane) (16B-aligned, bank-skewed).
    const char* oaB = (const char*)bw + (PAD2 + 144 * lane + (((lane >> 3) & 7) << 4));
    const float q25 = 0.25f;                // SGPR for v_fma_mix

    f32x2 P = { (lane == 0) ? 1.0f : 0.0f, 0.0f };  // (p1E, p1O); K[0,0]=1
    f32x2 U = { 0.0f, 0.0f };                        // (up2, p2E)
    f32x2 F = { -1.0f, -1.0f };                      // F.y = oF(0) = -1

    // 3 chunks in flight (load-to-use distance = 2 full chunk-iterations).
    uint4 cA = *(const uint4*)(oaB +  0);
    uint4 cB = *(const uint4*)(oaB + 16);
    uint4 cC = *(const uint4*)(oaB + 32);

    #pragma unroll
    for (int c = 0; c < 15; ++c) {
        // consume chunk c: bodies 8c+1 .. 8c+8
        PBODY8(cA)
        // rotate + prefetch chunk c+3 (chunks 0..15 cover oA[0..127])
        cA = cB; cB = cC;
        if (c <= 12) cC = *(const uint4*)(oaB + 16 * (c + 3));
    }
    // tail: bodies 121..126 from chunk 15 (slots x.lo .. z.hi)
    PBODYv(cvtLO(cA.x, q25)) PBODYv(cvtHI(cA.x, q25))
    PBODYv(cvtLO(cA.y, q25)) PBODYv(cvtHI(cA.y, q25))
    PBODYv(cvtLO(cA.z, q25)) PBODYv(cvtHI(cA.z, q25))

    // K[126,126] = lane 63's E slot after diagonal 252. Plain store, no atomic.
    if (lane == 63) {
        float w = (g == 1) ? (-2.0f / 1024.0f) : (1.0f / 1024.0f);
        pws[p] = w * P.x;
    }
}

__global__ __launch_bounds__(256) void reduce_kernel(const float* __restrict__ pws,
                                                     float* __restrict__ out) {
    // Sum 3072 weighted partials (768 float4 loads), write out[0].
    float s = 0.0f;
    const float4* v = (const float4*)pws;
    for (int i = threadIdx.x; i < 768; i += 256) {
        float4 t = v[i];
        s += (t.x + t.y) + (t.z + t.w);
    }
    for (int off = 32; off > 0; off >>= 1) s += __shfl_down(s, off);
    __shared__ float ws[4];
    if ((threadIdx.x & 63) == 0) ws[threadIdx.x >> 6] = s;
    __syncthreads();
    if (threadIdx.x == 0) out[0] = (ws[0] + ws[1]) + (ws[2] + ws[3]);
}

extern "C" void kernel_launch(void* const* d_in, const int* in_sizes, int n_in,
                              void* d_out, int out_size, void* d_ws, size_t ws_size,
                              hipStream_t stream) {
    const float* x = (const float*)d_in[0];
    const float* y = (const float*)d_in[1];
    float* out = (float*)d_out;
    float* pws = (float*)d_ws;    // 3072 floats = 12 KB << ws_size
    (void)in_sizes; (void)n_in; (void)out_size; (void)ws_size;

    hipLaunchKernelGGL(sigpde_kernel, dim3(768), dim3(256), 0, stream, x, y, pws);
    hipLaunchKernelGGL(reduce_kernel, dim3(1), dim3(256), 0, stream, pws, out);
}